// Round 6
// baseline (106.774 us; speedup 1.0000x reference)
//
#include <hip/hip_runtime.h>

// 16-qubit, 2-layer circuit, batch 32.  Circuit = P*R1*P*R0 (P = CNOT-ring permutation).
// f(i) = i ^ (i>>1) ^ (bit0(i)?0xC000:0);  f^{-1} = suffix-xor cascade.
// Cooperative fused kernel, per-batch atomic producer/consumer sync, with checked
// fallback to the equivalent 3-kernel path.
// R6: float2-packed LDS (b64 ops), phase C across all 512 blocks (j8 gate via one LDS
// re-tile), XCD-affinity block remap (batch = blk&7 + 8*(blk>>7)), padded counters.

#define NT 256

__device__ __forceinline__ int fperm(int x) {
  int y = x ^ (x >> 1);
  y ^= (x & 1) ? 0xC000 : 0;
  return y & 0xFFFF;
}

__device__ __forceinline__ int finv16(int x) {
  int s = x;
  s ^= s >> 1; s ^= s >> 2; s ^= s >> 4; s ^= s >> 8;
  int b15 = ((s ^ (s >> 15)) & 1) << 15;
  return (s & 0x7FFF) | b15;
}

// float2-index swizzle: bank-pair = idx % 16; xor-fold keeps every round pattern
// uniform (4 lanes per bank-pair per wave64).
__device__ __forceinline__ int swz(int l) { return l ^ ((l >> 4) & 15); }

__device__ __forceinline__ void compute_gates(const float* __restrict__ th, float* gsh) {
  int tid = threadIdx.x;
  if (tid < 32) {
    int l = tid >> 4, q = tid & 15;
    float tx = th[l * 48 + q], ty = th[l * 48 + 16 + q], tz = th[l * 48 + 32 + q];
    float cx, sx, cy, sy, cz, sz;
    sincosf(0.5f * tx, &sx, &cx);
    sincosf(0.5f * ty, &sy, &cy);
    sincosf(0.5f * tz, &sz, &cz);
    float m00r = cy * cx, m00i =  sy * sx;
    float m01r = -sy * cx, m01i = -cy * sx;
    float m10r =  sy * cx, m10i = -cy * sx;
    float m11r =  cy * cx, m11i = -sy * sx;
    float* G = gsh + tid * 8;
    G[0] = cz * m00r + sz * m00i;  G[1] = cz * m00i - sz * m00r;
    G[2] = cz * m01r + sz * m01i;  G[3] = cz * m01i - sz * m01r;
    G[4] = cz * m10r - sz * m10i;  G[5] = cz * m10i + sz * m10r;
    G[6] = cz * m11r - sz * m11i;  G[7] = cz * m11i + sz * m11r;
  }
}

template <int MK, int SK, int N>
__device__ __forceinline__ void greg(float2 (&a)[N], const float* G, int c) {
  const float4* G4 = (const float4*)G;
  float4 r0 = G4[0], r1 = G4[1];
  bool sw = (c != 0);
  float h00r = sw ? r1.z : r0.x, h00i = sw ? r1.w : r0.y;
  float h01r = sw ? r1.x : r0.z, h01i = sw ? r1.y : r0.w;
  float h10r = sw ? r0.z : r1.x, h10i = sw ? r0.w : r1.y;
  float h11r = sw ? r0.x : r1.z, h11i = sw ? r0.y : r1.w;
  constexpr int PV = MK & (-MK);
#pragma unroll
  for (int k = 0; k < N; k++) {
    if (k & PV) continue;
    const int k2 = k ^ MK;
    const int p0 = __builtin_popcount(k & SK) & 1;
    const int ka = p0 ? k2 : k;
    const int kb = p0 ? k : k2;
    float2 x = a[ka], y = a[kb];
    a[ka] = make_float2(h00r * x.x - h00i * x.y + h01r * y.x - h01i * y.y,
                        h00r * x.y + h00i * x.x + h01r * y.y + h01i * y.x);
    a[kb] = make_float2(h10r * x.x - h10i * x.y + h11r * y.x - h11i * y.y,
                        h10r * x.y + h10i * x.x + h11r * y.y + h11i * y.x);
  }
}

// ====================== Phase bodies ======================

__device__ __forceinline__ void phaseA_body(int t, int bbase, int wb,
                                            const float* gsh, float2* samp,
                                            const float* __restrict__ xre,
                                            const float* __restrict__ xim,
                                            float2* __restrict__ ws) {
  float2 a[16];
  int base = bbase + (wb << 12);
  const float4* xr4 = (const float4*)(xre + base + (t << 4));
  const float4* xi4 = (const float4*)(xim + base + (t << 4));
#pragma unroll
  for (int q = 0; q < 4; q++) {
    float4 v = xr4[q], w = xi4[q];
    a[4*q+0] = make_float2(v.x, w.x); a[4*q+1] = make_float2(v.y, w.y);
    a[4*q+2] = make_float2(v.z, w.z); a[4*q+3] = make_float2(v.w, w.w);
  }
  __syncthreads();   // gsh ready (and samp free)
  greg<1, 1>(a, gsh + 15 * 8, 0);
  greg<2, 2>(a, gsh + 14 * 8, 0);
  greg<4, 4>(a, gsh + 13 * 8, 0);
  greg<8, 8>(a, gsh + 12 * 8, 0);
#pragma unroll
  for (int k = 0; k < 16; k++) samp[swz((t << 4) | k)] = a[k];
  __syncthreads();
  // Round B: tile bits 4-7
#pragma unroll
  for (int k = 0; k < 16; k++)
    a[k] = samp[swz((t & 15) | (k << 4) | ((t >> 4) << 8))];
  greg<1, 1>(a, gsh + 11 * 8, 0);
  greg<2, 2>(a, gsh + 10 * 8, 0);
  greg<4, 4>(a, gsh + 9 * 8, 0);
  greg<8, 8>(a, gsh + 8 * 8, 0);
#pragma unroll
  for (int k = 0; k < 16; k++)
    samp[swz((t & 15) | (k << 4) | ((t >> 4) << 8))] = a[k];
  __syncthreads();
  // Round C: tile bits 8-11
#pragma unroll
  for (int k = 0; k < 16; k++) a[k] = samp[swz(t | (k << 8))];
  greg<1, 1>(a, gsh + 7 * 8, 0);
  greg<2, 2>(a, gsh + 6 * 8, 0);
  greg<4, 4>(a, gsh + 5 * 8, 0);
  greg<8, 8>(a, gsh + 4 * 8, 0);
#pragma unroll
  for (int k = 0; k < 16; k++)
    ws[base + t + (k << 8)] = a[k];
}

__device__ __forceinline__ void phaseB_body(int t, int bbase, int wb,
                                            const float* gsh, float2* samp,
                                            float2* __restrict__ ws) {
  float2 a[16];
#pragma unroll
  for (int k = 0; k < 16; k++)
    a[k] = ws[bbase + t + (wb << 8) + (k << 12)];
  int cA = (__popc(t) + __popc(wb)) & 1;   // parity of full bits 0..11
  greg<1, 1>(a, gsh + 3 * 8, 0);
  greg<2, 2>(a, gsh + 2 * 8, 0);
  greg<4, 4>(a, gsh + 1 * 8, 0);
  greg<8, 8>(a, gsh + 0 * 8, 0);
  greg<12, 7>(a, gsh + (16 + 0) * 8, cA);
  greg<6, 12>(a, gsh + (16 + 1) * 8, 0);
  greg<3, 14>(a, gsh + (16 + 2) * 8, 0);
  __syncthreads();   // samp free
#pragma unroll
  for (int k = 0; k < 16; k++) samp[swz(t | (k << 8))] = a[k];
  __syncthreads();
  // Round B': tile full {0,1,14,15}
#pragma unroll
  for (int k = 0; k < 16; k++)
    a[k] = samp[swz((k & 3) | (t << 2) | ((k >> 2) << 10))];
  greg<13, 15>(a, gsh + (16 + 15) * 8, cA);
  greg<3, 14>(a, gsh + (16 + 14) * 8, cA);
#pragma unroll
  for (int k = 0; k < 16; k++)
    samp[swz((k & 3) | (t << 2) | ((k >> 2) << 10))] = a[k];
  __syncthreads();
  // Round C': tile full {1,2,3,4}
#pragma unroll
  for (int k = 0; k < 16; k++)
    a[k] = samp[swz((t & 1) | (k << 1) | ((t >> 1) << 5))];
  {
    int cC = (__popc(t >> 1) + __popc(wb)) & 1;
    greg<3, 14>(a, gsh + (16 + 13) * 8, cC);
    greg<6, 12>(a, gsh + (16 + 12) * 8, cC);
    greg<12, 8>(a, gsh + (16 + 11) * 8, cC);
  }
#pragma unroll
  for (int k = 0; k < 16; k++)
    samp[swz((t & 1) | (k << 1) | ((t >> 1) << 5))] = a[k];
  __syncthreads();
  // Round D': tile full {4,5,6,7}; store to ws
#pragma unroll
  for (int k = 0; k < 16; k++)
    a[k] = samp[swz((t & 15) | (k << 4) | ((t >> 4) << 8))];
  {
    int cD = (__popc(t >> 4) + __popc(wb)) & 1;
    greg<3, 14>(a, gsh + (16 + 10) * 8, cD);
    greg<6, 12>(a, gsh + (16 + 9) * 8, cD);
    greg<12, 8>(a, gsh + (16 + 8) * 8, cD);
  }
#pragma unroll
  for (int k = 0; k < 16; k++) {
    int full = (t & 15) | (k << 4) | (wb << 8) | ((t >> 4) << 12);
    ws[bbase + full] = a[k];
  }
}

// Phase C across 512 blocks: block fixed j-bits {7,13,14,15} = wb; thread t -> j-bits
// {0..6,8}; k -> j-bits 9..12 (register gates).  j8 gate via one LDS re-tile
// (local l = t | k<<8; re-tile k'' -> local bits {7,8,9,10}).
__device__ __forceinline__ void phaseC_body(int t, int bbase, int wb,
                                            const float* gsh, float2* samp,
                                            const float2* __restrict__ ws,
                                            float* __restrict__ out) {
  int fix = ((wb & 1) << 7) | ((wb >> 1) << 13);
  int jt = (t & 127) | ((t >> 7) << 8) | fix;
  float2 a[16];
#pragma unroll
  for (int k = 0; k < 16; k++) {
    int j = jt | (k << 9);
    a[k] = ws[bbase + fperm(j)];
  }
  greg<1, 1>(a, gsh + (16 + 6) * 8, 0);   // j-bit 9  (qubit 6)
  greg<2, 2>(a, gsh + (16 + 5) * 8, 0);   // j-bit 10
  greg<4, 4>(a, gsh + (16 + 4) * 8, 0);   // j-bit 11
  greg<8, 8>(a, gsh + (16 + 3) * 8, 0);   // j-bit 12
#pragma unroll
  for (int k = 0; k < 16; k++) samp[swz(t | (k << 8))] = a[k];
  __syncthreads();
#pragma unroll
  for (int k = 0; k < 16; k++)
    a[k] = samp[swz((t & 127) | (k << 7) | ((t >> 7) << 11))];
  greg<1, 1>(a, gsh + (16 + 7) * 8, 0);   // j-bit 8 (qubit 7) = local bit 7 = k bit 0
#pragma unroll
  for (int k = 0; k < 16; k++) {
    int l = (t & 127) | (k << 7) | ((t >> 7) << 11);
    int j = (l & 127) | (((l >> 7) & 1) << 8) | ((l >> 8) << 9) | fix;
    out[bbase + finv16(j)] = a[k].x * a[k].x + a[k].y * a[k].y;
  }
}

// ====================== Fallback: 3-kernel path ======================

__global__ void __launch_bounds__(NT, 2) pass1_k(const float* __restrict__ th,
                                                 const float* __restrict__ xre,
                                                 const float* __restrict__ xim,
                                                 float2* __restrict__ ws) {
  __shared__ float gsh[256];
  __shared__ float2 samp[4096];
  int t = threadIdx.x, blk = blockIdx.x;
  int batch = (blk & 7) + ((blk >> 7) << 3), wb = (blk >> 3) & 15;
  compute_gates(th, gsh);
  phaseA_body(t, batch << 16, wb, gsh, samp, xre, xim, ws);
}

__global__ void __launch_bounds__(NT, 2) pass2_k(const float* __restrict__ th,
                                                 float2* __restrict__ ws) {
  __shared__ float gsh[256];
  __shared__ float2 samp[4096];
  int t = threadIdx.x, blk = blockIdx.x;
  int batch = (blk & 7) + ((blk >> 7) << 3), wb = (blk >> 3) & 15;
  compute_gates(th, gsh);
  __syncthreads();
  phaseB_body(t, batch << 16, wb, gsh, samp, ws);
}

__global__ void __launch_bounds__(NT, 2) pass3_k(const float* __restrict__ th,
                                                 const float2* __restrict__ ws,
                                                 float* __restrict__ out) {
  __shared__ float gsh[256];
  __shared__ float2 samp[4096];
  int t = threadIdx.x, blk = blockIdx.x;
  int batch = (blk & 7) + ((blk >> 7) << 3), wb = (blk >> 3) & 15;
  compute_gates(th, gsh);
  __syncthreads();
  phaseC_body(t, batch << 16, wb, gsh, samp, ws, out);
}

// ====================== Cooperative fused kernel ======================

__device__ __forceinline__ void signal(unsigned* cnt) {
  __threadfence();
  __syncthreads();
  if (threadIdx.x == 0)
    __hip_atomic_fetch_add(cnt, 1u, __ATOMIC_RELEASE, __HIP_MEMORY_SCOPE_AGENT);
}

__device__ __forceinline__ void wait16(unsigned* cnt) {
  if (threadIdx.x == 0) {
    while (__hip_atomic_load(cnt, __ATOMIC_ACQUIRE, __HIP_MEMORY_SCOPE_AGENT) < 16u)
      __builtin_amdgcn_s_sleep(2);
  }
  __syncthreads();
  __threadfence();
}

__global__ void __launch_bounds__(NT, 2)
fused_k(const float* __restrict__ th,
        const float* __restrict__ xre, const float* __restrict__ xim,
        float2* __restrict__ ws, float* __restrict__ out,
        unsigned* __restrict__ cnt1, unsigned* __restrict__ cnt2) {
  __shared__ float gsh[256];
  __shared__ float2 samp[4096];
  int t = threadIdx.x, blk = blockIdx.x;
  // XCD-affinity remap: all blocks of batch b share blk%8 == b&7 (L2 locality heuristic).
  int batch = (blk & 7) + ((blk >> 7) << 3), wb = (blk >> 3) & 15;
  int bbase = batch << 16;

  compute_gates(th, gsh);
  phaseA_body(t, bbase, wb, gsh, samp, xre, xim, ws);
  signal(&cnt1[batch << 5]);

  wait16(&cnt1[batch << 5]);
  phaseB_body(t, bbase, wb, gsh, samp, ws);
  signal(&cnt2[batch << 5]);

  wait16(&cnt2[batch << 5]);
  phaseC_body(t, bbase, wb, gsh, samp, ws, out);
}

// ====================== Launcher ======================

extern "C" void kernel_launch(void* const* d_in, const int* in_sizes, int n_in,
                              void* d_out, int out_size, void* d_ws, size_t ws_size,
                              hipStream_t stream) {
  const float* th  = (const float*)d_in[0];   // (2,3,16)
  const float* xre = (const float*)d_in[1];   // (32,65536)
  const float* xim = (const float*)d_in[2];   // (32,65536)
  float* out = (float*)d_out;                 // (32,65536) fp32

  float2* amp = (float2*)d_ws;                              // 16 MB state
  unsigned* cnt1 = (unsigned*)((char*)d_ws + (16u << 20));  // padded: 32 uints/counter
  unsigned* cnt2 = cnt1 + 1024;

  int maxBlk = 0;
  hipError_t qrc = hipOccupancyMaxActiveBlocksPerMultiprocessor(
      &maxBlk, (const void*)fused_k, NT, 0);
  bool try_coop = (qrc == hipSuccess && maxBlk >= 2);

  bool coop_ok = false;
  if (try_coop) {
    hipMemsetAsync((void*)cnt1, 0, 2048 * sizeof(unsigned), stream);
    void* args[] = {(void*)&th, (void*)&xre, (void*)&xim,
                    (void*)&amp, (void*)&out, (void*)&cnt1, (void*)&cnt2};
    hipError_t rc = hipLaunchCooperativeKernel((const void*)fused_k, dim3(512),
                                               dim3(NT), args, 0, stream);
    coop_ok = (rc == hipSuccess);
  }

  if (!coop_ok) {
    pass1_k<<<512, NT, 0, stream>>>(th, xre, xim, amp);
    pass2_k<<<512, NT, 0, stream>>>(th, amp);
    pass3_k<<<512, NT, 0, stream>>>(th, amp, out);
  }
}

// Round 7
// 104.530 us; speedup vs baseline: 1.0215x; 1.0215x over previous
//
#include <hip/hip_runtime.h>
#include <hip/hip_fp16.h>

// 16-qubit, 2-layer circuit, batch 32.  Circuit = P*R1*P*R0 (P = CNOT-ring permutation).
// f(i) = i ^ (i>>1) ^ (bit0(i)?0xC000:0);  f^{-1} = suffix-xor cascade.
// R7: plain 3-kernel path (coop fusion proven neutral in R5/R6), fp16-packed ws
// (halves boundary traffic; compute stays fp32), nontemporal final-out stores.
// All index / gate / selector algebra verbatim from the R6-verified bodies.

#define NT 256

__device__ __forceinline__ int fperm(int x) {
  int y = x ^ (x >> 1);
  y ^= (x & 1) ? 0xC000 : 0;
  return y & 0xFFFF;
}

__device__ __forceinline__ int finv16(int x) {
  int s = x;
  s ^= s >> 1; s ^= s >> 2; s ^= s >> 4; s ^= s >> 8;
  int b15 = ((s ^ (s >> 15)) & 1) << 15;
  return (s & 0x7FFF) | b15;
}

__device__ __forceinline__ int swz(int l) { return l ^ ((l >> 4) & 15); }

__device__ __forceinline__ __half2 packa(float2 a) {
  return __floats2half2_rn(a.x, a.y);
}
__device__ __forceinline__ float2 unpacka(__half2 h) {
  return __half22float2(h);
}

__device__ __forceinline__ void compute_gates(const float* __restrict__ th, float* gsh) {
  int tid = threadIdx.x;
  if (tid < 32) {
    int l = tid >> 4, q = tid & 15;
    float tx = th[l * 48 + q], ty = th[l * 48 + 16 + q], tz = th[l * 48 + 32 + q];
    float cx, sx, cy, sy, cz, sz;
    sincosf(0.5f * tx, &sx, &cx);
    sincosf(0.5f * ty, &sy, &cy);
    sincosf(0.5f * tz, &sz, &cz);
    float m00r = cy * cx, m00i =  sy * sx;
    float m01r = -sy * cx, m01i = -cy * sx;
    float m10r =  sy * cx, m10i = -cy * sx;
    float m11r =  cy * cx, m11i = -sy * sx;
    float* G = gsh + tid * 8;
    G[0] = cz * m00r + sz * m00i;  G[1] = cz * m00i - sz * m00r;
    G[2] = cz * m01r + sz * m01i;  G[3] = cz * m01i - sz * m01r;
    G[4] = cz * m10r - sz * m10i;  G[5] = cz * m10i + sz * m10r;
    G[6] = cz * m11r - sz * m11i;  G[7] = cz * m11i + sz * m11r;
  }
}

template <int MK, int SK, int N>
__device__ __forceinline__ void greg(float2 (&a)[N], const float* G, int c) {
  const float4* G4 = (const float4*)G;
  float4 r0 = G4[0], r1 = G4[1];
  bool sw = (c != 0);
  float h00r = sw ? r1.z : r0.x, h00i = sw ? r1.w : r0.y;
  float h01r = sw ? r1.x : r0.z, h01i = sw ? r1.y : r0.w;
  float h10r = sw ? r0.z : r1.x, h10i = sw ? r0.w : r1.y;
  float h11r = sw ? r0.x : r1.z, h11i = sw ? r0.y : r1.w;
  constexpr int PV = MK & (-MK);
#pragma unroll
  for (int k = 0; k < N; k++) {
    if (k & PV) continue;
    const int k2 = k ^ MK;
    const int p0 = __builtin_popcount(k & SK) & 1;
    const int ka = p0 ? k2 : k;
    const int kb = p0 ? k : k2;
    float2 x = a[ka], y = a[kb];
    a[ka] = make_float2(h00r * x.x - h00i * x.y + h01r * y.x - h01i * y.y,
                        h00r * x.y + h00i * x.x + h01r * y.y + h01i * y.x);
    a[kb] = make_float2(h10r * x.x - h10i * x.y + h11r * y.x - h11i * y.y,
                        h10r * x.y + h10i * x.x + h11r * y.y + h11i * y.x);
  }
}

// ====================== Pass 1: R0 on bits 0..11 ======================

__global__ void __launch_bounds__(NT, 2) pass1_k(const float* __restrict__ th,
                                                 const float* __restrict__ xre,
                                                 const float* __restrict__ xim,
                                                 __half2* __restrict__ ws) {
  __shared__ float gsh[256];
  __shared__ float2 samp[4096];
  int t = threadIdx.x, blk = blockIdx.x;
  int batch = (blk & 7) + ((blk >> 7) << 3), wb = (blk >> 3) & 15;
  int bbase = batch << 16;
  float2 a[16];
  int base = bbase + (wb << 12);
  const float4* xr4 = (const float4*)(xre + base + (t << 4));
  const float4* xi4 = (const float4*)(xim + base + (t << 4));
#pragma unroll
  for (int q = 0; q < 4; q++) {
    float4 v = xr4[q], w = xi4[q];
    a[4*q+0] = make_float2(v.x, w.x); a[4*q+1] = make_float2(v.y, w.y);
    a[4*q+2] = make_float2(v.z, w.z); a[4*q+3] = make_float2(v.w, w.w);
  }
  compute_gates(th, gsh);
  __syncthreads();   // gsh ready
  greg<1, 1>(a, gsh + 15 * 8, 0);
  greg<2, 2>(a, gsh + 14 * 8, 0);
  greg<4, 4>(a, gsh + 13 * 8, 0);
  greg<8, 8>(a, gsh + 12 * 8, 0);
#pragma unroll
  for (int k = 0; k < 16; k++) samp[swz((t << 4) | k)] = a[k];
  __syncthreads();
  // Round B: tile bits 4-7
#pragma unroll
  for (int k = 0; k < 16; k++)
    a[k] = samp[swz((t & 15) | (k << 4) | ((t >> 4) << 8))];
  greg<1, 1>(a, gsh + 11 * 8, 0);
  greg<2, 2>(a, gsh + 10 * 8, 0);
  greg<4, 4>(a, gsh + 9 * 8, 0);
  greg<8, 8>(a, gsh + 8 * 8, 0);
#pragma unroll
  for (int k = 0; k < 16; k++)
    samp[swz((t & 15) | (k << 4) | ((t >> 4) << 8))] = a[k];
  __syncthreads();
  // Round C: tile bits 8-11
#pragma unroll
  for (int k = 0; k < 16; k++) a[k] = samp[swz(t | (k << 8))];
  greg<1, 1>(a, gsh + 7 * 8, 0);
  greg<2, 2>(a, gsh + 6 * 8, 0);
  greg<4, 4>(a, gsh + 5 * 8, 0);
  greg<8, 8>(a, gsh + 4 * 8, 0);
#pragma unroll
  for (int k = 0; k < 16; k++)
    ws[base + t + (k << 8)] = packa(a[k]);
}

// ====== Pass 2: R0 bits 12-15 + conj-R1 b in {0..7,13,14,15} (window bits 8-11) ======

__global__ void __launch_bounds__(NT, 2) pass2_k(const float* __restrict__ th,
                                                 __half2* __restrict__ ws) {
  __shared__ float gsh[256];
  __shared__ float2 samp[4096];
  int t = threadIdx.x, blk = blockIdx.x;
  int batch = (blk & 7) + ((blk >> 7) << 3), wb = (blk >> 3) & 15;
  int bbase = batch << 16;
  float2 a[16];
#pragma unroll
  for (int k = 0; k < 16; k++)
    a[k] = unpacka(ws[bbase + t + (wb << 8) + (k << 12)]);
  compute_gates(th, gsh);
  __syncthreads();   // gsh ready
  int cA = (__popc(t) + __popc(wb)) & 1;   // parity of full bits 0..11
  greg<1, 1>(a, gsh + 3 * 8, 0);
  greg<2, 2>(a, gsh + 2 * 8, 0);
  greg<4, 4>(a, gsh + 1 * 8, 0);
  greg<8, 8>(a, gsh + 0 * 8, 0);
  greg<12, 7>(a, gsh + (16 + 0) * 8, cA);
  greg<6, 12>(a, gsh + (16 + 1) * 8, 0);
  greg<3, 14>(a, gsh + (16 + 2) * 8, 0);
#pragma unroll
  for (int k = 0; k < 16; k++) samp[swz(t | (k << 8))] = a[k];
  __syncthreads();
  // Round B': tile full {0,1,14,15}
#pragma unroll
  for (int k = 0; k < 16; k++)
    a[k] = samp[swz((k & 3) | (t << 2) | ((k >> 2) << 10))];
  greg<13, 15>(a, gsh + (16 + 15) * 8, cA);
  greg<3, 14>(a, gsh + (16 + 14) * 8, cA);
#pragma unroll
  for (int k = 0; k < 16; k++)
    samp[swz((k & 3) | (t << 2) | ((k >> 2) << 10))] = a[k];
  __syncthreads();
  // Round C': tile full {1,2,3,4}
#pragma unroll
  for (int k = 0; k < 16; k++)
    a[k] = samp[swz((t & 1) | (k << 1) | ((t >> 1) << 5))];
  {
    int cC = (__popc(t >> 1) + __popc(wb)) & 1;
    greg<3, 14>(a, gsh + (16 + 13) * 8, cC);
    greg<6, 12>(a, gsh + (16 + 12) * 8, cC);
    greg<12, 8>(a, gsh + (16 + 11) * 8, cC);
  }
#pragma unroll
  for (int k = 0; k < 16; k++)
    samp[swz((t & 1) | (k << 1) | ((t >> 1) << 5))] = a[k];
  __syncthreads();
  // Round D': tile full {4,5,6,7}; store
#pragma unroll
  for (int k = 0; k < 16; k++)
    a[k] = samp[swz((t & 15) | (k << 4) | ((t >> 4) << 8))];
  {
    int cD = (__popc(t >> 4) + __popc(wb)) & 1;
    greg<3, 14>(a, gsh + (16 + 10) * 8, cD);
    greg<6, 12>(a, gsh + (16 + 9) * 8, cD);
    greg<12, 8>(a, gsh + (16 + 8) * 8, cD);
  }
#pragma unroll
  for (int k = 0; k < 16; k++) {
    int full = (t & 15) | (k << 4) | (wb << 8) | ((t >> 4) << 12);
    ws[bbase + full] = packa(a[k]);
  }
}

// ====== Pass 3: gather B[f(j)], R1 on j-bits 8..12, out[f^{-1}(j)] = |amp|^2 ======
// Block fixes j-bits {7,13,14,15}=wb; thread t -> j-bits {0..6,8}; k -> j-bits 9..12.
// j8 gate via one LDS re-tile.

__global__ void __launch_bounds__(NT, 2) pass3_k(const float* __restrict__ th,
                                                 const __half2* __restrict__ ws,
                                                 float* __restrict__ out) {
  __shared__ float gsh[256];
  __shared__ float2 samp[4096];
  int t = threadIdx.x, blk = blockIdx.x;
  int batch = (blk & 7) + ((blk >> 7) << 3), wb = (blk >> 3) & 15;
  int bbase = batch << 16;
  int fix = ((wb & 1) << 7) | ((wb >> 1) << 13);
  int jt = (t & 127) | ((t >> 7) << 8) | fix;
  float2 a[16];
#pragma unroll
  for (int k = 0; k < 16; k++) {
    int j = jt | (k << 9);
    a[k] = unpacka(ws[bbase + fperm(j)]);
  }
  compute_gates(th, gsh);
  __syncthreads();   // gsh ready
  greg<1, 1>(a, gsh + (16 + 6) * 8, 0);   // j-bit 9  (qubit 6)
  greg<2, 2>(a, gsh + (16 + 5) * 8, 0);   // j-bit 10
  greg<4, 4>(a, gsh + (16 + 4) * 8, 0);   // j-bit 11
  greg<8, 8>(a, gsh + (16 + 3) * 8, 0);   // j-bit 12
#pragma unroll
  for (int k = 0; k < 16; k++) samp[swz(t | (k << 8))] = a[k];
  __syncthreads();
#pragma unroll
  for (int k = 0; k < 16; k++)
    a[k] = samp[swz((t & 127) | (k << 7) | ((t >> 7) << 11))];
  greg<1, 1>(a, gsh + (16 + 7) * 8, 0);   // j-bit 8 (qubit 7) = local bit 7 = k bit 0
#pragma unroll
  for (int k = 0; k < 16; k++) {
    int l = (t & 127) | (k << 7) | ((t >> 7) << 11);
    int j = (l & 127) | (((l >> 7) & 1) << 8) | ((l >> 8) << 9) | fix;
    float pr = a[k].x * a[k].x + a[k].y * a[k].y;
    __builtin_nontemporal_store(pr, &out[bbase + finv16(j)]);
  }
}

// ====================== Launcher ======================

extern "C" void kernel_launch(void* const* d_in, const int* in_sizes, int n_in,
                              void* d_out, int out_size, void* d_ws, size_t ws_size,
                              hipStream_t stream) {
  const float* th  = (const float*)d_in[0];   // (2,3,16)
  const float* xre = (const float*)d_in[1];   // (32,65536)
  const float* xim = (const float*)d_in[2];   // (32,65536)
  float* out = (float*)d_out;                 // (32,65536) fp32

  __half2* amp = (__half2*)d_ws;              // 2M half2 = 8 MB state

  pass1_k<<<512, NT, 0, stream>>>(th, xre, xim, amp);
  pass2_k<<<512, NT, 0, stream>>>(th, amp);
  pass3_k<<<512, NT, 0, stream>>>(th, amp, out);
}